// Round 7
// baseline (513.796 us; speedup 1.0000x reference)
//
#include <hip/hip_runtime.h>
#include <stdint.h>

// Problem constants (S,M,H,E fixed by setup_inputs; C = ceil(K*S/E) aligned to 4 = 1024)
#define S_TOK 4096
#define MDIM  1024
#define HDIM  4096
#define NEXP  8
#define CAP   1024

typedef __attribute__((ext_vector_type(4))) float f4;
typedef __attribute__((ext_vector_type(8))) short short8;
typedef __attribute__((ext_vector_type(4))) unsigned short us4;
typedef __attribute__((ext_vector_type(8))) unsigned short us8;

__device__ __forceinline__ unsigned short f2bf(float f) {
  union { float f; unsigned int u; } v; v.f = f;
  unsigned int u = v.u;
  unsigned int r = (u + 0x7FFFu + ((u >> 16) & 1u)) >> 16;  // RNE
  return (unsigned short)r;
}

// async global->LDS, 16B per lane; LDS dest = wave-uniform base + lane*16
__device__ __forceinline__ void async16(const unsigned short* gp, unsigned short* lp_wave_base) {
  __builtin_amdgcn_global_load_lds(
      (const __attribute__((address_space(1))) unsigned int*)gp,
      (__attribute__((address_space(3))) unsigned int*)lp_wave_base,
      16, 0, 0);
}

// ---------------- gating: logits (fp32), softmax, top-2, gates ----------------
__global__ __launch_bounds__(256) void gating_kernel(
    const float* __restrict__ x, const float* __restrict__ wg,
    float* __restrict__ scores, int* __restrict__ topk_ids,
    float* __restrict__ gates)
{
  int wave = threadIdx.x >> 6, lane = threadIdx.x & 63;
  int s = blockIdx.x * 4 + wave;
  const float* xs = x + (size_t)s * MDIM;
  float acc[8];
#pragma unroll
  for (int e = 0; e < 8; ++e) acc[e] = 0.f;
#pragma unroll
  for (int j = 0; j < 4; ++j) {
    f4 xv = *(const f4*)(xs + j * 256 + lane * 4);
#pragma unroll
    for (int i = 0; i < 4; ++i) {
      int m = j * 256 + lane * 4 + i;
      const f4* w = (const f4*)(wg + (size_t)m * 8);
      f4 w0 = w[0], w1 = w[1];
      acc[0] += xv[i] * w0[0]; acc[1] += xv[i] * w0[1];
      acc[2] += xv[i] * w0[2]; acc[3] += xv[i] * w0[3];
      acc[4] += xv[i] * w1[0]; acc[5] += xv[i] * w1[1];
      acc[6] += xv[i] * w1[2]; acc[7] += xv[i] * w1[3];
    }
  }
#pragma unroll
  for (int e = 0; e < 8; ++e) {
    float v = acc[e];
    for (int off = 32; off; off >>= 1) v += __shfl_xor(v, off, 64);
    acc[e] = v;
  }
  if (lane == 0) {
    float mx = acc[0];
#pragma unroll
    for (int e = 1; e < 8; ++e) mx = fmaxf(mx, acc[e]);
    float p[8], tot = 0.f;
#pragma unroll
    for (int e = 0; e < 8; ++e) { p[e] = expf(acc[e] - mx); tot += p[e]; }
    float inv = 1.f / tot;
#pragma unroll
    for (int e = 0; e < 8; ++e) { p[e] *= inv; scores[s * 8 + e] = p[e]; }
    // top-2 with lowest-index tie-break (strict >), matching lax.top_k
    int i0 = 0;
#pragma unroll
    for (int e = 1; e < 8; ++e) if (p[e] > p[i0]) i0 = e;
    int i1 = -1;
#pragma unroll
    for (int e = 0; e < 8; ++e) {
      if (e == i0) continue;
      if (i1 < 0 || p[e] > p[i1]) i1 = e;
    }
    float v0 = p[i0], v1 = p[i1];
    float den = fmaxf(v0 + v1, 1e-7f);
    topk_ids[s * 2] = i0; topk_ids[s * 2 + 1] = i1;
    gates[s * 2] = v0 / den; gates[s * 2 + 1] = v1 / den;
  }
}

// ---------- assignment: exact ordered capacity scan (k-major over 8192 entries) ----------
// Outputs per expert-row: row_src (source token or -1), row_gate (combine weight).
__global__ __launch_bounds__(1024) void assign_kernel(
    const int* __restrict__ topk_ids, const float* __restrict__ gates,
    int* __restrict__ row_src, float* __restrict__ row_gate)
{
  __shared__ unsigned long long sc0[1024], sc1[1024];
  int t = threadIdx.x;
#pragma unroll
  for (int j = 0; j < 8; ++j) row_src[t * 8 + j] = -1;  // all 8192 rows

  int e8[8];
  unsigned long long c0 = 0, c1 = 0;
  int base = t * 8;
#pragma unroll
  for (int j = 0; j < 8; ++j) {
    int i = base + j;
    int k = i >> 12, s = i & 4095;     // i = k*4096 + s (k-major = reference offset order)
    int e = topk_ids[s * 2 + k];
    e8[j] = e;
    if (e < 4) c0 += 1ull << (16 * e); else c1 += 1ull << (16 * (e - 4));
  }
  sc0[t] = c0; sc1[t] = c1;
  __syncthreads();
  for (int off = 1; off < 1024; off <<= 1) {
    unsigned long long a0 = 0, a1 = 0;
    if (t >= off) { a0 = sc0[t - off]; a1 = sc1[t - off]; }
    __syncthreads();
    sc0[t] += a0; sc1[t] += a1;
    __syncthreads();
  }
  unsigned long long r0 = 0, r1 = 0;
  if (t > 0) { r0 = sc0[t - 1]; r1 = sc1[t - 1]; }
#pragma unroll
  for (int j = 0; j < 8; ++j) {
    int i = base + j;
    int k = i >> 12, s = i & 4095;
    int e = e8[j];
    int loc = (e < 4) ? (int)((r0 >> (16 * e)) & 0xFFFFull)
                      : (int)((r1 >> (16 * (e - 4))) & 0xFFFFull);
    if (e < 4) r0 += 1ull << (16 * e); else r1 += 1ull << (16 * (e - 4));
    if (loc < CAP) {
      int flat = e * CAP + loc;
      row_src[flat] = s;
      row_gate[flat] = gates[s * 2 + k];
    }
  }
}

// ---------------- dispatch: y[row] = bf16(x[src]) or zeros; 2 rows per block ----------------
__global__ __launch_bounds__(256) void dispatch_kernel(
    const float* __restrict__ x, const int* __restrict__ row_src,
    unsigned short* __restrict__ y)
{
  int r = blockIdx.x * 2 + (threadIdx.x >> 7);
  int s = row_src[r];
  int m0 = (threadIdx.x & 127) * 8;
  us8 o;
  if (s >= 0) {
    f4 v0 = *(const f4*)(x + (size_t)s * MDIM + m0);
    f4 v1 = *(const f4*)(x + (size_t)s * MDIM + m0 + 4);
#pragma unroll
    for (int i = 0; i < 4; ++i) { o[i] = f2bf(v0[i]); o[4 + i] = f2bf(v1[i]); }
  } else {
#pragma unroll
    for (int i = 0; i < 8; ++i) o[i] = 0;
  }
  *(us8*)(y + (size_t)r * MDIM + m0) = o;
}

// -------- weight convert+transpose: in [E,R,Cc] fp32 -> out [E,Cc,R] bf16 --------
// 64x64 tile staged as fp32 in LDS (stride 68 words, f4 16B-aligned bank-balanced writes);
// transposed b32 reads + convert + us8 (16B) coalesced stores.
// Weight reads are NON-TEMPORAL (`nt`): fp32 weights are stream-once; keep them from
// evicting the live L3 set that the GEMMs depend on. (r2: ~-44us total vs plain loads.)
__global__ __launch_bounds__(256) void convT_kernel(
    const float* __restrict__ in, unsigned short* __restrict__ out,
    int R, int Cc)
{
  __shared__ float tile[64 * 68];
  int e = blockIdx.z;
  int c0 = blockIdx.x * 64, r0 = blockIdx.y * 64;
  int t = threadIdx.x;
  const float* ine = in + (size_t)e * R * Cc;
  unsigned short* oute = out + (size_t)e * Cc * R;

  int cg = t & 15, rr = t >> 4;  // load map: 16 col-groups of 4 floats x 16 rows
#pragma unroll
  for (int p = 0; p < 4; ++p) {
    int r = rr + 16 * p;
    f4 v = __builtin_nontemporal_load(
        (const f4*)(ine + (size_t)(r0 + r) * Cc + c0 + cg * 4));
    *(f4*)&tile[r * 68 + cg * 4] = v;
  }
  __syncthreads();
  int c = t >> 3, rb = t & 7;    // store map: 32 cols x 8 r-chunks per pass
#pragma unroll
  for (int p = 0; p < 2; ++p) {
    int cc = c + 32 * p;
    us8 o;
#pragma unroll
    for (int i = 0; i < 8; ++i) o[i] = f2bf(tile[(rb * 8 + i) * 68 + cc]);
    *(us8*)(oute + (size_t)(c0 + cc) * R + r0 + rb * 8) = o;
  }
}

// ---------------- bf16 MFMA GEMM, B^T operand, expert-batched, XCD-swizzled ----------------
// 8 waves (512 threads) per 128x128 tile; wave grid 2(M)x4(N), 64x32 sub-tile per wave.
// K-loop: T4 counted-vmcnt pipeline, K-step 32, FOUR 16KB LDS buffers, prefetch depth 3:
//   body(t): STAGE(t+3) -> COMPUTE(t) -> s_waitcnt vmcnt(4) lgkmcnt(0) -> s_barrier
// Three stages (2 loads each) stay in flight across barriers; vmcnt(4) retires exactly the
// oldest stage; never drains vmcnt to 0 in the loop.
// *** lgkmcnt(0) before the barrier is REQUIRED (r6 failed without it): buf[t&3] is
// rewritten by STAGE(t+4) only ONE barrier after COMPUTE(t) reads it, so each wave must
// prove its ds_reads have sampled LDS before releasing the next writer. s_barrier alone
// does not wait on LDS ops (cdna4_isa §8); under 16-wave LDS congestion a pending
// ds_read raced the next tile's DMA write -> r6's small nondeterministic absmax fail. ***
// Safety ledger: buffer written at t -> computed at t+3 (vmcnt(4)+barrier chain) ->
// rewritten at t+4 (lgkmcnt(0)+barrier). Pre-loop hoisted scalar loads only cause
// earlier stage retirement (safe; ledger self-syncs within 3 iterations).
// rowfast: tile-order swap. GEMM1 uses bRow-fastest so consecutive 8 blocks share one
// B-panel (512KB, L2-hot) and the A-expert (2MB) goes L2-resident -> B streams once
// (r5 measured bCol-fastest GEMM1 at 235MB fetch vs 80MB unique).
// fuse=0: out bf16 = (relu? max(v+b,0) : v+b), LDS-staged us8 stores.
// fuse=1: combine epilogue: atomicAdd(out[token, col], gate * (v+b)) via row_src/row_gate.
__global__ __launch_bounds__(512, 4) void gemm_bt(
    const unsigned short* __restrict__ A, const unsigned short* __restrict__ Bt,
    const float* __restrict__ bias, unsigned short* __restrict__ Cout,
    int RA, int N, int K, int relu, int gxmask, int gxshift, int rowfast,
    int fuse, const int* __restrict__ row_src, const float* __restrict__ row_gate,
    float* __restrict__ out)
{
  int lin = blockIdx.x;
  int e = lin & 7;
  int tt = lin >> 3;
  int i0 = tt & gxmask, i1 = tt >> gxshift;
  int bRow, bCol;
  if (rowfast) { bRow = i0 * 128; bCol = i1 * 128; }
  else         { bCol = i0 * 128; bRow = i1 * 128; }

  const unsigned short* Ae = A  + (size_t)e * RA * K;
  const unsigned short* Be = Bt + (size_t)e * N  * K;
  const float* be = bias + (size_t)e * N;

  // 64KB: 4 K-step buffers of 8192 shorts each = A[128][32] + B[128][32] (linear [row][k]).
  __shared__ __align__(16) unsigned short LDSbuf[32768];

  int tid = threadIdx.x;
  int lane = tid & 63, wave = tid >> 6;      // 8 waves
  int wr = wave >> 2, wc = wave & 3;         // 2 (M) x 4 (N)
  int q = lane >> 4, r16 = lane & 15;

  // staging map: chunk ci in [0,512): row=ci>>2, k-offset=(ci&3)*8; LDS dest shorts =
  // wave*512 + lane*8 == row*32 + c8 (matches layout; wave-uniform base rule ok).
  int ci = wave * 64 + lane;
  int srow = ci >> 2, sc8 = (ci & 3) * 8;
  const unsigned short* agp = Ae + (size_t)(bRow + srow) * K + sc8;
  const unsigned short* bgp = Be + (size_t)(bCol + srow) * K + sc8;

  f4 acc[4][2] = {};

  auto STAGE = [&](int t) {
    unsigned short* buf = LDSbuf + (t & 3) * 8192;
    async16(agp + t * 32, buf + wave * 512);
    async16(bgp + t * 32, buf + 4096 + wave * 512);
  };
  auto COMPUTE = [&](int t) {
    const unsigned short* buf = LDSbuf + (t & 3) * 8192;
    short8 af[4], bf[2];
#pragma unroll
    for (int mt = 0; mt < 4; ++mt)
      af[mt] = *(const short8*)&buf[(wr * 64 + mt * 16 + r16) * 32 + q * 8];
#pragma unroll
    for (int nn = 0; nn < 2; ++nn)
      bf[nn] = *(const short8*)&buf[4096 + (wc * 32 + nn * 16 + r16) * 32 + q * 8];
#pragma unroll
    for (int mt = 0; mt < 4; ++mt)
#pragma unroll
      for (int nn = 0; nn < 2; ++nn)
        acc[mt][nn] = __builtin_amdgcn_mfma_f32_16x16x32_bf16(af[mt], bf[nn], acc[mt][nn], 0, 0, 0);
  };

  int ntk = K >> 5;  // K-steps of 32 (>=32 for both GEMMs)
  STAGE(0); STAGE(1); STAGE(2);
  asm volatile("s_waitcnt vmcnt(4)" ::: "memory");   // stage 0 resident (own wave)
  __builtin_amdgcn_s_barrier();                      // ... for all waves
  __builtin_amdgcn_sched_barrier(0);
  for (int t = 0; t < ntk - 3; ++t) {
    STAGE(t + 3);                                    // overwrites buf read 1 barrier ago
    COMPUTE(t);
    // vmcnt(4): retire oldest stage (t+1). lgkmcnt(0): my ds_reads of buf[t&3] have
    // sampled LDS -- REQUIRED before releasing STAGE(t+4) (r6 race).
    asm volatile("s_waitcnt vmcnt(4) lgkmcnt(0)" ::: "memory");
    __builtin_amdgcn_s_barrier();
    __builtin_amdgcn_sched_barrier(0);
  }
  COMPUTE(ntk - 3);
  asm volatile("s_waitcnt vmcnt(2) lgkmcnt(0)" ::: "memory");
  __builtin_amdgcn_s_barrier();
  __builtin_amdgcn_sched_barrier(0);
  COMPUTE(ntk - 2);
  asm volatile("s_waitcnt vmcnt(0) lgkmcnt(0)" ::: "memory");
  __builtin_amdgcn_s_barrier();
  __builtin_amdgcn_sched_barrier(0);
  COMPUTE(ntk - 1);
  __syncthreads();                                   // full drain; LDS reused by epilogue

  // C/D layout: col=lane&15, row=quad*4+reg (verified m89/m91)
  float bv[2];
#pragma unroll
  for (int nn = 0; nn < 2; ++nn) bv[nn] = be[bCol + wc * 32 + nn * 16 + r16];

  if (!fuse) {
    // stage wave's 64x32 bf16 tile in its private 4KB LDS slice, then 16B stores
    unsigned short* ep = LDSbuf + wave * 2048;
#pragma unroll
    for (int mt = 0; mt < 4; ++mt)
#pragma unroll
      for (int nn = 0; nn < 2; ++nn)
#pragma unroll
        for (int r = 0; r < 4; ++r) {
          float v = acc[mt][nn][r] + bv[nn];
          if (relu) v = fmaxf(v, 0.f);
          ep[(mt * 16 + q * 4 + r) * 32 + nn * 16 + r16] = f2bf(v);
        }
    // 64 rows x 32 cols: 4 passes of 64 lanes x 16B
#pragma unroll
    for (int pass = 0; pass < 4; ++pass) {
      int row = pass * 16 + (lane >> 2);
      int seg = lane & 3;
      us8 v = *(const us8*)&ep[row * 32 + seg * 8];
      *(us8*)&Cout[((size_t)e * RA + bRow + wr * 64 + row) * N + bCol + wc * 32 + seg * 8] = v;
    }
  } else {
    // fused combine: each expert row -> token s with gate g; out[s] += g * (acc + bias)
#pragma unroll
    for (int mt = 0; mt < 4; ++mt)
#pragma unroll
      for (int r = 0; r < 4; ++r) {
        int grow = e * RA + bRow + wr * 64 + mt * 16 + q * 4 + r;
        int s = row_src[grow];
        if (s < 0) continue;
        float g = row_gate[grow];
#pragma unroll
        for (int nn = 0; nn < 2; ++nn) {
          float v = acc[mt][nn][r] + bv[nn];
          atomicAdd(out + (size_t)s * N + bCol + wc * 32 + nn * 16 + r16, g * v);
        }
      }
  }
}

// ---------------- l_aux: deterministic single-block reduction ----------------
__global__ __launch_bounds__(256) void aux_kernel(
    const float* __restrict__ scores, const int* __restrict__ topk_ids,
    float* __restrict__ laux_out)
{
  __shared__ float red[256];
  __shared__ float msum[8], csum[8];
  int t = threadIdx.x;
  float me[8], ce[8];
#pragma unroll
  for (int e = 0; e < 8; ++e) { me[e] = 0.f; ce[e] = 0.f; }
  for (int s = t; s < S_TOK; s += 256) {
#pragma unroll
    for (int e = 0; e < 8; ++e) me[e] += scores[s * 8 + e];
    int top = topk_ids[s * 2];
#pragma unroll
    for (int e = 0; e < 8; ++e) ce[e] += (top == e) ? 1.f : 0.f;
  }
  for (int e = 0; e < 8; ++e) {
    red[t] = me[e]; __syncthreads();
    for (int off = 128; off; off >>= 1) { if (t < off) red[t] += red[t + off]; __syncthreads(); }
    if (t == 0) msum[e] = red[0];
    __syncthreads();
  }
  for (int e = 0; e < 8; ++e) {
    red[t] = ce[e]; __syncthreads();
    for (int off = 128; off; off >>= 1) { if (t < off) red[t] += red[t + off]; __syncthreads(); }
    if (t == 0) csum[e] = red[0];
    __syncthreads();
  }
  if (t == 0) {
    float l = 0.f;
#pragma unroll
    for (int e = 0; e < 8; ++e)
      l += (msum[e] / (float)S_TOK) * (csum[e] / (float)S_TOK);
    laux_out[0] = l * (float)NEXP;
  }
}

extern "C" void kernel_launch(void* const* d_in, const int* in_sizes, int n_in,
                              void* d_out, int out_size, void* d_ws, size_t ws_size,
                              hipStream_t stream) {
  const float* x     = (const float*)d_in[0];
  const float* wg    = (const float*)d_in[1];
  const float* fc1_w = (const float*)d_in[2];
  const float* fc1_b = (const float*)d_in[3];
  const float* fc2_w = (const float*)d_in[4];
  const float* fc2_b = (const float*)d_in[5];
  float* out = (float*)d_out;

  // workspace carve-out (~208 MB total)
  char* ws = (char*)d_ws;
  size_t off = 0;
  auto alloc = [&](size_t b) { size_t o = off; off += (b + 255) & ~(size_t)255; return o; };
  unsigned short* fc1T = (unsigned short*)(ws + alloc((size_t)NEXP * HDIM * MDIM * 2)); // [E,H,M] bf16
  unsigned short* fc2T = (unsigned short*)(ws + alloc((size_t)NEXP * MDIM * HDIM * 2)); // [E,M,H] bf16
  unsigned short* y    = (unsigned short*)(ws + alloc((size_t)NEXP * CAP * MDIM * 2));  // [E*C,M] bf16
  unsigned short* h    = (unsigned short*)(ws + alloc((size_t)NEXP * CAP * HDIM * 2));  // [E*C,H] bf16
  float* scores        = (float*)(ws + alloc((size_t)S_TOK * 8 * 4));
  int*   topk          = (int*)(ws + alloc((size_t)S_TOK * 2 * 4));
  float* gates         = (float*)(ws + alloc((size_t)S_TOK * 2 * 4));
  int*   row_src       = (int*)(ws + alloc((size_t)NEXP * CAP * 4));
  float* row_gate      = (float*)(ws + alloc((size_t)NEXP * CAP * 4));

  // zero-init output (combine epilogue accumulates atomically into it)
  hipMemsetAsync(d_out, 0, (size_t)out_size * 4, stream);

  // Both weight transposes BEFORE GEMM1 (nt reads; fc2T stays L3-hot for GEMM2's B).
  convT_kernel<<<dim3(HDIM / 64, MDIM / 64, NEXP), 256, 0, stream>>>(fc1_w, fc1T, MDIM, HDIM);
  convT_kernel<<<dim3(MDIM / 64, HDIM / 64, NEXP), 256, 0, stream>>>(fc2_w, fc2T, HDIM, MDIM);

  gating_kernel<<<dim3(S_TOK / 4), 256, 0, stream>>>(x, wg, scores, topk, gates);
  assign_kernel<<<dim3(1), 1024, 0, stream>>>(topk, gates, row_src, row_gate);
  dispatch_kernel<<<dim3(NEXP * CAP / 2), 256, 0, stream>>>(x, row_src, y);

  // h = relu(y @ fc1_w + fc1_b): RA=C, N=H, K=M; 2048 blocks, rowfast=1 (8 row-tiles
  // innermost -> B-panel shared by consecutive blocks, A-expert L2-resident, B streams once)
  gemm_bt<<<dim3(2048), 512, 0, stream>>>(y, fc1T, fc1_b, h, CAP, HDIM, MDIM, 1, 7, 3, 1,
                                          0, nullptr, nullptr, nullptr);

  // out[token] += gate * (h @ fc2_w + fc2_b): RA=C, N=M, K=H; 512 blocks, rowfast=0
  // (A=h panel L2-hot per row-sweep, read once from HBM; B=fc2T re-reads hit L3)
  gemm_bt<<<dim3(512), 512, 0, stream>>>(h, fc2T, fc2_b, nullptr, CAP, MDIM, HDIM, 0, 7, 3, 0,
                                         1, row_src, row_gate, out);

  aux_kernel<<<dim3(1), 256, 0, stream>>>(scores, topk, out + (size_t)S_TOK * MDIM);
}